// Round 4
// baseline (476.455 us; speedup 1.0000x reference)
//
#include <hip/hip_runtime.h>

#define TPB 256
#define SCAN_B 256
#define NB 512           // CSR-fill buckets
#define BPAD 16          // bucket counter padding (ints) -> one 64B line each

typedef __attribute__((ext_vector_type(8))) short bf16x8;
typedef __attribute__((ext_vector_type(4))) float f32x4;

// ---------- fp32 -> bf16 hi/lo split ----------
__device__ inline void split1(float x, unsigned short& h, unsigned short& l) {
  unsigned xb = __float_as_uint(x);
  h = (unsigned short)(xb >> 16);
  float hf = __uint_as_float(xb & 0xFFFF0000u);
  float lf = x - hf;
  l = (unsigned short)(__float_as_uint(lf) >> 16);
}

__device__ inline void split4(const float4 v, ushort4& h, ushort4& l) {
  split1(v.x, h.x, l.x);
  split1(v.y, h.y, l.y);
  split1(v.z, h.z, l.z);
  split1(v.w, h.w, l.w);
}

// ---------- degree / rowptr ----------

__global__ void k_hist(const int* __restrict__ dst, int* __restrict__ cnt, int E) {
  int e = blockIdx.x * blockDim.x + threadIdx.x;
  if (e < E) atomicAdd(cnt + dst[e], 1);
}

__global__ void k_dinv_from_cnt(const int* __restrict__ cnt, float* __restrict__ dinv, int N) {
  int i = blockIdx.x * blockDim.x + threadIdx.x;
  if (i < N) dinv[i] = rsqrtf((float)(cnt[i] + 1));
}

__global__ void k_scanA(const int* __restrict__ cnt, int* __restrict__ rowptr1,
                        int* __restrict__ bsum, int N) {
  __shared__ int s[SCAN_B];
  int i = blockIdx.x * SCAN_B + threadIdx.x;
  int v = (i < N) ? cnt[i] : 0;
  s[threadIdx.x] = v;
  __syncthreads();
  for (int off = 1; off < SCAN_B; off <<= 1) {
    int t = (threadIdx.x >= (unsigned)off) ? s[threadIdx.x - off] : 0;
    __syncthreads();
    s[threadIdx.x] += t;
    __syncthreads();
  }
  if (i < N) rowptr1[i] = s[threadIdx.x];
  if (threadIdx.x == SCAN_B - 1) bsum[blockIdx.x] = s[SCAN_B - 1];
}

__global__ void k_scanB(int* __restrict__ bsum, int nb) {
  __shared__ int s[1024];
  int v = (threadIdx.x < (unsigned)nb) ? bsum[threadIdx.x] : 0;
  s[threadIdx.x] = v;
  __syncthreads();
  for (int off = 1; off < 1024; off <<= 1) {
    int t = (threadIdx.x >= (unsigned)off) ? s[threadIdx.x - off] : 0;
    __syncthreads();
    s[threadIdx.x] += t;
    __syncthreads();
  }
  if (threadIdx.x < (unsigned)nb) bsum[threadIdx.x] = s[threadIdx.x] - v;
}

__global__ void k_scanC(int* __restrict__ rowptr, const int* __restrict__ bsum, int N) {
  int i = blockIdx.x * SCAN_B + threadIdx.x;
  if (i < N) rowptr[i + 1] += bsum[blockIdx.x];
  if (i == 0) rowptr[0] = 0;
}

__global__ void k_copy_i32(int* __restrict__ d, const int* __restrict__ s, int n) {
  int i = blockIdx.x * blockDim.x + threadIdx.x;
  if (i < n) d[i] = s[i];
}

// ---------- bucketed CSR fill (dense write streams, no 16x write-amp) ----------

__global__ void k_bcount(const int* __restrict__ dst, int* __restrict__ bcnt, int E, int bpn) {
  int stride = gridDim.x * blockDim.x;
  for (int e = blockIdx.x * blockDim.x + threadIdx.x; e < E; e += stride)
    atomicAdd(bcnt + (dst[e] / bpn) * BPAD, 1);
}

// 1 block of NB threads: boff = exclusive scan(bcnt), bpos = boff (cursors), boff[NB] = E
__global__ void k_bscan(const int* __restrict__ bcnt, int* __restrict__ boff,
                        int* __restrict__ bpos) {
  __shared__ int s[NB];
  int v = bcnt[threadIdx.x * BPAD];
  s[threadIdx.x] = v;
  __syncthreads();
  for (int off = 1; off < NB; off <<= 1) {
    int t = (threadIdx.x >= (unsigned)off) ? s[threadIdx.x - off] : 0;
    __syncthreads();
    s[threadIdx.x] += t;
    __syncthreads();
  }
  int excl = s[threadIdx.x] - v;
  boff[threadIdx.x] = excl;
  bpos[threadIdx.x * BPAD] = excl;
  if (threadIdx.x == NB - 1) boff[NB] = s[NB - 1];
}

__global__ void k_bfill(const int* __restrict__ src, const int* __restrict__ dst,
                        int* __restrict__ bpos, uint2* __restrict__ bdata, int E, int bpn) {
  int stride = gridDim.x * blockDim.x;
  for (int e = blockIdx.x * blockDim.x + threadIdx.x; e < E; e += stride) {
    int d = dst[e];
    int p = atomicAdd(bpos + (d / bpn) * BPAD, 1);
    bdata[p] = make_uint2((unsigned)src[e], (unsigned)d);
  }
}

// one block per bucket: contiguous reads, col writes land in a small window
__global__ void k_bcsr(const uint2* __restrict__ bdata, const int* __restrict__ boff,
                       const int* __restrict__ rowptr, int* __restrict__ col, int bpn) {
  __shared__ int lcnt[256];   // bpn <= 256 required
  const int b = blockIdx.x;
  const int nodeBase = b * bpn;
  for (int i = threadIdx.x; i < bpn; i += blockDim.x) lcnt[i] = 0;
  __syncthreads();
  const int beg = boff[b], end = boff[b + 1];
  for (int i = beg + threadIdx.x; i < end; i += blockDim.x) {
    uint2 ed = bdata[i];
    int node = (int)ed.y;
    int s = atomicAdd(&lcnt[node - nodeBase], 1);
    col[rowptr[node] + s] = (int)ed.x;
  }
}

// plain fillcsr (middle-fallback only)
__global__ void k_fillcsr(const int* __restrict__ src, const int* __restrict__ dst,
                          int* __restrict__ wpos, int* __restrict__ col, int E) {
  int e = blockIdx.x * blockDim.x + threadIdx.x;
  if (e >= E) return;
  int p = atomicAdd(wpos + dst[e], 1);
  col[p] = src[e];
}

// ---------- W prep: W[K][C] f32 -> Wt_hi/lo[C][K] bf16 (transposed + split) ----------
__global__ void k_prep_wt(const float* __restrict__ W, unsigned short* __restrict__ Wh,
                          unsigned short* __restrict__ Wl, int K, int C) {
  int i = blockIdx.x * blockDim.x + threadIdx.x;
  if (i >= K * C) return;
  int k = i / C, c = i % C;
  unsigned short h, l;
  split1(W[i], h, l);
  Wh[(size_t)c * K + k] = h;
  Wl[(size_t)c * K + k] = l;
}

// ---------- MFMA GEMM: Y[N,COUT] = (X[N,128] @ W[128,COUT]) * dinv[row] ----------
template<int COUT>
__launch_bounds__(512)
__global__ void k_gemm_mfma(const float* __restrict__ X, const unsigned short* __restrict__ Wh,
                            const unsigned short* __restrict__ Wl, const float* __restrict__ dinv,
                            float* __restrict__ Y, int N) {
  constexpr int K = 128;
  constexpr int BM = 128;
  constexpr int WCOL = COUT / 2;
  constexpr int NFRAG = WCOL / 16;
  __shared__ unsigned short Ah[BM * K], Al[BM * K];
  __shared__ unsigned short Wsh[COUT * K], Wsl[COUT * K];

  const int tid = threadIdx.x;
  const int rb = blockIdx.x * BM;

  {
    const uint4* gh = (const uint4*)Wh;
    const uint4* gl = (const uint4*)Wl;
    for (int i = tid; i < COUT * 16; i += 512) {
      int r = i >> 4, c = i & 15;
      int byte = r * 256 + ((c * 16) ^ ((r & 7) << 4));
      *(uint4*)((char*)Wsh + byte) = gh[i];
      *(uint4*)((char*)Wsl + byte) = gl[i];
    }
  }
  {
    for (int i = tid; i < BM * 32; i += 512) {
      int r = i >> 5, c4 = i & 31;
      int g = rb + r;
      if (g < N) {
        float4 v = ((const float4*)(X + (size_t)g * K))[c4];
        ushort4 h, l;
        split4(v, h, l);
        int byte = r * 256 + ((c4 * 8) ^ ((r & 7) << 4));
        *(ushort4*)((char*)Ah + byte) = h;
        *(ushort4*)((char*)Al + byte) = l;
      }
    }
  }
  __syncthreads();

  const int wid = tid >> 6, lane = tid & 63;
  const int wm = wid & 3;
  const int wn = wid >> 2;
  const int RB = wm * 32;
  const int CB = wn * WCOL;
  const int l15 = lane & 15, l4 = lane >> 4;
  const int xs = (l15 & 7) << 4;

  f32x4 acc[2][NFRAG];
  #pragma unroll
  for (int m = 0; m < 2; ++m)
    #pragma unroll
    for (int n = 0; n < NFRAG; ++n)
      acc[m][n] = (f32x4){0.f, 0.f, 0.f, 0.f};

  #pragma unroll
  for (int ks = 0; ks < 4; ++ks) {
    const int cbx = (ks * 64 + l4 * 16) ^ xs;
    bf16x8 a0h = *(const bf16x8*)((const char*)Ah + (RB + l15) * 256 + cbx);
    bf16x8 a0l = *(const bf16x8*)((const char*)Al + (RB + l15) * 256 + cbx);
    bf16x8 a1h = *(const bf16x8*)((const char*)Ah + (RB + 16 + l15) * 256 + cbx);
    bf16x8 a1l = *(const bf16x8*)((const char*)Al + (RB + 16 + l15) * 256 + cbx);
    #pragma unroll
    for (int n = 0; n < NFRAG; ++n) {
      const int wr = CB + n * 16 + l15;
      bf16x8 bh = *(const bf16x8*)((const char*)Wsh + wr * 256 + cbx);
      bf16x8 bl = *(const bf16x8*)((const char*)Wsl + wr * 256 + cbx);
      acc[0][n] = __builtin_amdgcn_mfma_f32_16x16x32_bf16(a0h, bh, acc[0][n], 0, 0, 0);
      acc[0][n] = __builtin_amdgcn_mfma_f32_16x16x32_bf16(a0h, bl, acc[0][n], 0, 0, 0);
      acc[0][n] = __builtin_amdgcn_mfma_f32_16x16x32_bf16(a0l, bh, acc[0][n], 0, 0, 0);
      acc[1][n] = __builtin_amdgcn_mfma_f32_16x16x32_bf16(a1h, bh, acc[1][n], 0, 0, 0);
      acc[1][n] = __builtin_amdgcn_mfma_f32_16x16x32_bf16(a1h, bl, acc[1][n], 0, 0, 0);
      acc[1][n] = __builtin_amdgcn_mfma_f32_16x16x32_bf16(a1l, bh, acc[1][n], 0, 0, 0);
    }
  }

  #pragma unroll
  for (int m = 0; m < 2; ++m) {
    #pragma unroll
    for (int q = 0; q < 4; ++q) {
      int row = rb + RB + m * 16 + l4 * 4 + q;
      if (row < N) {
        float dv = dinv[row];
        float* yr = Y + (size_t)row * COUT + CB + l15;
        #pragma unroll
        for (int n = 0; n < NFRAG; ++n) yr[n * 16] = acc[m][n][q] * dv;
      }
    }
  }
}

// ---------- vector GEMM (fallback path only) ----------
template<int COUT>
__launch_bounds__(256)
__global__ void k_gemm128(const float* __restrict__ X, const float* __restrict__ W,
                          const float* __restrict__ dinv, float* __restrict__ Y, int N) {
  constexpr int K = 128;
  constexpr int CG = COUT / 8;
  constexpr int ROWS = 256 / CG;
  constexpr int XSTR = K + 4;
  __shared__ float Ws[K * COUT];
  __shared__ float Xs[ROWS * XSTR];
  const int tid = threadIdx.x;

  const float4* W4 = (const float4*)W;
  float4* Ws4 = (float4*)Ws;
  #pragma unroll
  for (int i = tid; i < K * COUT / 4; i += 256) Ws4[i] = W4[i];

  const int rb = blockIdx.x * ROWS;
  float4* Xs4 = (float4*)Xs;
  for (int i = tid; i < ROWS * (K / 4); i += 256) {
    int r = i / (K / 4), c = i % (K / 4);
    float4 v = make_float4(0.f, 0.f, 0.f, 0.f);
    if (rb + r < N) v = ((const float4*)(X + (size_t)(rb + r) * K))[c];
    Xs4[r * (XSTR / 4) + c] = v;
  }
  __syncthreads();

  const int lrow = tid / CG;
  const int cg = tid % CG;
  const int row = rb + lrow;
  float acc[8];
  #pragma unroll
  for (int j = 0; j < 8; ++j) acc[j] = 0.f;
  const float* xr = Xs + lrow * XSTR;
  #pragma unroll 4
  for (int k = 0; k < K; ++k) {
    float xv = xr[k];
    float4 w0 = Ws4[k * (COUT / 4) + cg * 2];
    float4 w1 = Ws4[k * (COUT / 4) + cg * 2 + 1];
    acc[0] = fmaf(xv, w0.x, acc[0]);
    acc[1] = fmaf(xv, w0.y, acc[1]);
    acc[2] = fmaf(xv, w0.z, acc[2]);
    acc[3] = fmaf(xv, w0.w, acc[3]);
    acc[4] = fmaf(xv, w1.x, acc[4]);
    acc[5] = fmaf(xv, w1.y, acc[5]);
    acc[6] = fmaf(xv, w1.z, acc[6]);
    acc[7] = fmaf(xv, w1.w, acc[7]);
  }
  if (row < N) {
    float ds = dinv[row];
    float4* y = (float4*)(Y + (size_t)row * COUT + cg * 8);
    y[0] = make_float4(acc[0] * ds, acc[1] * ds, acc[2] * ds, acc[3] * ds);
    y[1] = make_float4(acc[4] * ds, acc[5] * ds, acc[6] * ds, acc[7] * ds);
  }
}

// ---------- CSR gather-aggregate ----------
template<int C>
__launch_bounds__(C)
__global__ void k_agg(const float* __restrict__ hs, const float* __restrict__ dinv,
                      const int* __restrict__ rowptr, const int* __restrict__ col,
                      const float* __restrict__ bias, float* __restrict__ out, int N) {
  const int node = blockIdx.x;
  const int tid = threadIdx.x;
  float acc = hs[(size_t)node * C + tid];
  const int beg = rowptr[node];
  const int end = rowptr[node + 1];
  __shared__ int nb[C];
  for (int base = beg; base < end; base += C) {
    int m = min(C, end - base);
    if (tid < m) nb[tid] = col[base + tid];
    __syncthreads();
    for (int k = 0; k < m; ++k) acc += hs[(size_t)nb[k] * C + tid];
    __syncthreads();
  }
  out[(size_t)node * C + tid] = fmaxf(fmaf(dinv[node], acc, bias[tid]), 0.f);
}

// ---------- fallback (atomic scatter) kernels ----------
__global__ void k_fill1(float* __restrict__ p, int n) {
  int i = blockIdx.x * blockDim.x + threadIdx.x;
  if (i < n) p[i] = 1.0f;
}
__global__ void k_deg_scatter(const int* __restrict__ dst, float* __restrict__ deg, int E) {
  int e = blockIdx.x * blockDim.x + threadIdx.x;
  if (e < E) atomicAdd(deg + dst[e], 1.0f);
}
__global__ void k_rsqrt_inplace(float* __restrict__ p, int n) {
  int i = blockIdx.x * blockDim.x + threadIdx.x;
  if (i < n) p[i] = rsqrtf(p[i]);
}
template<int C>
__global__ void k_selfinit2(const float* __restrict__ hs, const float* __restrict__ dinv,
                            float* __restrict__ agg, int N) {
  int i = blockIdx.x * blockDim.x + threadIdx.x;
  int total = N * (C / 4);
  if (i >= total) return;
  int node = i / (C / 4);
  float di = dinv[node];
  float4 v = ((const float4*)hs)[i];
  ((float4*)agg)[i] = make_float4(v.x * di, v.y * di, v.z * di, v.w * di);
}
template<int C>
__global__ void k_scatter(const float* __restrict__ hs, const float* __restrict__ dinv,
                          const int* __restrict__ src, const int* __restrict__ dst,
                          float* __restrict__ agg, int E) {
  constexpr int LPE = C / 4;
  long long t = (long long)blockIdx.x * blockDim.x + threadIdx.x;
  int e = (int)(t / LPE);
  if (e >= E) return;
  int c4 = (int)(t % LPE);
  int s = src[e], d = dst[e];
  float nd = dinv[d];
  float4 v = ((const float4*)(hs + (size_t)s * C))[c4];
  float* a = agg + (size_t)d * C + (size_t)c4 * 4;
  atomicAdd(a + 0, v.x * nd);
  atomicAdd(a + 1, v.y * nd);
  atomicAdd(a + 2, v.z * nd);
  atomicAdd(a + 3, v.w * nd);
}
template<int C>
__global__ void k_relu_bias(const float* __restrict__ agg, const float* __restrict__ b,
                            float* __restrict__ out, int N) {
  int i = blockIdx.x * blockDim.x + threadIdx.x;
  int total = N * (C / 4);
  if (i >= total) return;
  int c4 = i % (C / 4);
  float4 bb = ((const float4*)b)[c4];
  float4 v = ((const float4*)agg)[i];
  v.x = fmaxf(v.x + bb.x, 0.f);
  v.y = fmaxf(v.y + bb.y, 0.f);
  v.z = fmaxf(v.z + bb.z, 0.f);
  v.w = fmaxf(v.w + bb.w, 0.f);
  ((float4*)out)[i] = v;
}

extern "C" void kernel_launch(void* const* d_in, const int* in_sizes, int n_in,
                              void* d_out, int out_size, void* d_ws, size_t ws_size,
                              hipStream_t stream) {
  const float* x  = (const float*)d_in[0];
  const int*   ei = (const int*)d_in[1];
  const float* W1 = (const float*)d_in[2];
  const float* b1 = (const float*)d_in[3];
  const float* W2 = (const float*)d_in[4];
  const float* b2 = (const float*)d_in[5];

  const int Cin = 128, Chid = 128, Cout2 = 64;
  const int N = in_sizes[0] / Cin;
  const int E = in_sizes[1] / 2;
  const int* src = ei;
  const int* dst = ei + E;
  float* out = (float*)d_out;
  (void)n_in; (void)out_size;

  const int nbN = (N + TPB - 1) / TPB;
  const int nbE = (E + TPB - 1) / TPB;
  const int nbScan = (N + SCAN_B - 1) / SCAN_B;  // <= 1024 required
  const int nT = (N + 127) / 128;
  const int bpn = (N + NB - 1) / NB;             // nodes per bucket (<= 256 required)

  auto align = [](size_t v) { return (v + 511) & ~(size_t)511; };
  char* ws = (char*)d_ws;
  size_t off = 0;
  float* dinv   = (float*)(ws + off); off += align((size_t)N * 4);
  int*   cnt    = (int*)(ws + off);   off += align((size_t)N * 4);
  int*   rowptr = (int*)(ws + off);   off += align((size_t)(N + 1) * 4);
  int*   bsum   = (int*)(ws + off);   off += align((size_t)nbScan * 4);
  unsigned short* wt1h = (unsigned short*)(ws + off); off += align((size_t)Cin * Chid * 2);
  unsigned short* wt1l = (unsigned short*)(ws + off); off += align((size_t)Cin * Chid * 2);
  unsigned short* wt2h = (unsigned short*)(ws + off); off += align((size_t)Chid * Cout2 * 2);
  unsigned short* wt2l = (unsigned short*)(ws + off); off += align((size_t)Chid * Cout2 * 2);
  int*   col    = (int*)(ws + off);   off += align((size_t)E * 4);
  float* A      = (float*)(ws + off); off += (size_t)N * Chid * 4;
  float* B      = (float*)(ws + off); off += (size_t)N * Chid * 4;
  const size_t off_csr = off;
  // bucket-path extras
  int*   bcnt  = (int*)(ws + off);  off += align((size_t)NB * BPAD * 4);
  int*   bpos  = (int*)(ws + off);  off += align((size_t)NB * BPAD * 4);
  int*   boff  = (int*)(ws + off);  off += align((size_t)(NB + 1) * 4);
  uint2* bdata = (uint2*)(ws + off); off += align((size_t)E * 8);

  const bool csr_ok = (off_csr <= ws_size) && (nbScan <= 1024);
  const bool bucket_ok = csr_ok && (off <= ws_size) && (bpn <= 256);

  if (csr_ok) {
    // ---- degree + rowptr ----
    hipMemsetAsync(cnt, 0, (size_t)N * 4, stream);
    k_hist<<<nbE, TPB, 0, stream>>>(dst, cnt, E);
    k_dinv_from_cnt<<<nbN, TPB, 0, stream>>>(cnt, dinv, N);
    k_scanA<<<nbScan, SCAN_B, 0, stream>>>(cnt, rowptr + 1, bsum, N);
    k_scanB<<<1, 1024, 0, stream>>>(bsum, nbScan);
    k_scanC<<<nbScan, SCAN_B, 0, stream>>>(rowptr, bsum, N);

    // ---- CSR col fill ----
    if (bucket_ok) {
      hipMemsetAsync(bcnt, 0, (size_t)NB * BPAD * 4, stream);
      k_bcount<<<2048, TPB, 0, stream>>>(dst, bcnt, E, bpn);
      k_bscan<<<1, NB, 0, stream>>>(bcnt, boff, bpos);
      k_bfill<<<2048, TPB, 0, stream>>>(src, dst, bpos, bdata, E, bpn);
      k_bcsr<<<NB, TPB, 0, stream>>>(bdata, boff, rowptr, col, bpn);
    } else {
      k_copy_i32<<<nbN, TPB, 0, stream>>>(cnt, rowptr, N);
      k_fillcsr<<<nbE, TPB, 0, stream>>>(src, dst, cnt, col, E);
    }

    // ---- W prep ----
    k_prep_wt<<<(Cin * Chid + TPB - 1) / TPB, TPB, 0, stream>>>(W1, wt1h, wt1l, Cin, Chid);
    k_prep_wt<<<(Chid * Cout2 + TPB - 1) / TPB, TPB, 0, stream>>>(W2, wt2h, wt2l, Chid, Cout2);

    // ---- layer 1: 128 -> 128 ----
    k_gemm_mfma<128><<<nT, 512, 0, stream>>>(x, wt1h, wt1l, dinv, A, N);
    k_agg<128><<<N, 128, 0, stream>>>(A, dinv, rowptr, col, b1, B, N);
    // ---- layer 2: 128 -> 64 ----
    k_gemm_mfma<64><<<nT, 512, 0, stream>>>(B, wt2h, wt2l, dinv, A, N);
    k_agg<64><<<N, 64, 0, stream>>>(A, dinv, rowptr, col, b2, out, N);
  } else {
    // ---- fallback: atomic-scatter path ----
    size_t o2 = 0;
    float* dinvF = (float*)(ws + o2); o2 += align((size_t)N * 4);
    float* AF = (float*)(ws + o2);    o2 += (size_t)N * Chid * 4;
    float* BF = (float*)(ws + o2);

    k_fill1<<<nbN, TPB, 0, stream>>>(dinvF, N);
    k_deg_scatter<<<nbE, TPB, 0, stream>>>(dst, dinvF, E);
    k_rsqrt_inplace<<<nbN, TPB, 0, stream>>>(dinvF, N);

    k_gemm128<128><<<(N + 15) / 16, 256, 0, stream>>>(x, W1, dinvF, AF, N);
    k_selfinit2<128><<<(N * 32 + TPB - 1) / TPB, TPB, 0, stream>>>(AF, dinvF, BF, N);
    {
      long long total = (long long)E * 32;
      k_scatter<128><<<(int)((total + TPB - 1) / TPB), TPB, 0, stream>>>(AF, dinvF, src, dst, BF, E);
    }
    k_relu_bias<128><<<(N * 32 + TPB - 1) / TPB, TPB, 0, stream>>>(BF, b1, AF, N);

    k_gemm128<64><<<(N + 31) / 32, 256, 0, stream>>>(AF, W2, dinvF, BF, N);
    k_selfinit2<64><<<(N * 16 + TPB - 1) / TPB, TPB, 0, stream>>>(BF, dinvF, out, N);
    {
      long long total = (long long)E * 16;
      k_scatter<64><<<(int)((total + TPB - 1) / TPB), TPB, 0, stream>>>(BF, dinvF, src, dst, out, E);
    }
    k_relu_bias<64><<<(N * 16 + TPB - 1) / TPB, TPB, 0, stream>>>(out, b2, out, N);
  }
}